// Round 15
// baseline (245.148 us; speedup 1.0000x reference)
//
#include <hip/hip_runtime.h>
#include <math.h>

#define DD 64      // feature dim
#define MM 128     // time points per path
#define RSW 132    // inc LDS row stride in words (b64-aligned pairs; 2-way banks)
#define P1W 2112   // plane-1 offset in words (16*RSW)
#define RS2 66     // row stride in float2 units

typedef float  f32x4v __attribute__((ext_vector_type(4)));
typedef __bf16 bf16x8 __attribute__((ext_vector_type(8)));

#define FOR8(F) F(0) F(1) F(2) F(3) F(4) F(5) F(6) F(7)

union FragU { unsigned int u[4]; bf16x8 v; };

__device__ __forceinline__ unsigned cvtpk(float lo, float hi) {
    unsigned r;
    asm("v_cvt_pk_bf16_f32 %0, %1, %2" : "=v"(r) : "v"(lo), "v"(hi));
    return r;
}

__device__ __forceinline__ bf16x8 dfrag_hi(const float* __restrict__ r0,
                                           const float* __restrict__ r1) {
    float4 a0 = *(const float4*)r0, a1 = *(const float4*)(r0 + 4);
    float4 b0 = *(const float4*)r1, b1 = *(const float4*)(r1 + 4);
    FragU f;
    f.u[0] = cvtpk(b0.x - a0.x, b0.y - a0.y);
    f.u[1] = cvtpk(b0.z - a0.z, b0.w - a0.w);
    f.u[2] = cvtpk(b1.x - a1.x, b1.y - a1.y);
    f.u[3] = cvtpk(b1.z - a1.z, b1.w - a1.w);
    return f.v;
}

template<int CTRL, int RM, bool BC>
__device__ __forceinline__ float dpp_add(float x) {
    int t = __builtin_amdgcn_update_dpp(0, __float_as_int(x), CTRL, RM, 0xf, BC);
    return x + __int_as_float(t);
}
__device__ __forceinline__ float wave_incl_scan(float x) {
    x = dpp_add<0x111, 0xf, true >(x);   // row_shr:1
    x = dpp_add<0x112, 0xf, true >(x);   // row_shr:2
    x = dpp_add<0x114, 0xf, true >(x);   // row_shr:4
    x = dpp_add<0x118, 0xf, true >(x);   // row_shr:8
    x = dpp_add<0x142, 0xa, false>(x);   // row_bcast:15 -> rows 1,3
    x = dpp_add<0x143, 0xc, false>(x);   // row_bcast:31 -> rows 2,3
    return x;
}

// shared macros (resolve against per-kernel locals)
#define CTSTEP2(ct) { \
        f32x4v c0 = {0.f, 0.f, 0.f, 0.f}, c1 = {0.f, 0.f, 0.f, 0.f}; \
        c0 = __builtin_amdgcn_mfma_f32_16x16x32_bf16(a0k0, tb0_##ct, c0, 0, 0, 0); \
        c1 = __builtin_amdgcn_mfma_f32_16x16x32_bf16(a1k0, tb0_##ct, c1, 0, 0, 0); \
        c0 = __builtin_amdgcn_mfma_f32_16x16x32_bf16(a0k1, tb1_##ct, c0, 0, 0, 0); \
        c1 = __builtin_amdgcn_mfma_f32_16x16x32_bf16(a1k1, tb1_##ct, c1, 0, 0, 0); \
        const int w_ = wbase + ct * 16; \
        incL[w_]              = c0[0]; \
        incL[w_ + RSW]        = c0[1]; \
        incL[w_ + 2*RSW]      = c0[2]; \
        incL[w_ + 3*RSW]      = c0[3]; \
        incL[P1W + w_]        = c1[0]; \
        incL[P1W + w_ + RSW]  = c1[1]; \
        incL[P1W + w_ + 2*RSW]= c1[2]; \
        incL[P1W + w_ + 3*RSW]= c1[3]; }

#define SCANROW2C(e0, e1) { \
        const float m0a = e0.x * s0e; \
        const float m1a = e0.y * s0o; \
        const float m0b = e1.x * s1e; \
        const float m1b = e1.y * s1o; \
        const float ta  = m0a + m1a; \
        const float tb  = m0b + m1b; \
        const float Sa  = wave_incl_scan(ta); \
        const float Sb  = wave_incl_scan(tb); \
        const float exa = Sa - ta; \
        const float exb = Sb - tb; \
        s0o += exa + m0a;  s0e += exa; \
        s1o += exb + m0b;  s1e += exb; }

#define TBDECL(ct) bf16x8 tb0_##ct, tb1_##ct;
#define TBUILD(ct) { int brow_ = ct * 16 + l15; if (brow_ > 126) brow_ = 126; \
        const float* vp_ = V + (size_t)brow_ * DD + k8; \
        tb0_##ct = dfrag_hi(vp_,      vp_ + DD); \
        tb1_##ct = dfrag_hi(vp_ + 32, vp_ + DD + 32); }

// ================= FULL (r11 verbatim — best known, correct output) =========
__global__ __launch_bounds__(64, 3) void sig_goursat_kernel(
        const float* __restrict__ X, const float* __restrict__ Y,
        float* __restrict__ Kout)
{
    const int bid = blockIdx.x;
    int g, a0, a1, bcol;
    bool dup = false;
    if (bid < 2112) {
        g = bid < 1056 ? 0 : 1;
        const int t = bid - g * 1056;
        bcol = (int)(2.0f * sqrtf((float)t + 1.0f));
        if (bcol > 63) bcol = 63;
        while (bcol > 0  && ((bcol + 1) * (bcol + 1)) / 4 > t) --bcol;
        while (bcol < 63 && ((bcol + 2) * (bcol + 2)) / 4 <= t) ++bcol;
        const int j = t - ((bcol + 1) * (bcol + 1)) / 4;
        a0 = 2 * j; a1 = 2 * j + 1;
        if (a1 > bcol) { a1 = a0; dup = true; }
    } else {
        const int t = bid - 2112;
        g = 2; bcol = t & 63;
        a0 = (t >> 6) * 2; a1 = a0 + 1;
    }

    const float* __restrict__ Ub = (g == 1 ? Y : X);
    const float* __restrict__ U0 = Ub + (size_t)a0 * (MM * DD);
    const float* __restrict__ U1 = Ub + (size_t)a1 * (MM * DD);
    const float* __restrict__ V  = (g == 0 ? X : Y) + (size_t)bcol * (MM * DD);

    const int lane = threadIdx.x;
    const int l15  = lane & 15;
    const int k8   = (lane >> 4) * 8;
    const int rowg = (lane >> 4) * 4;

    __shared__ float incL[2 * P1W];

    FOR8(TBDECL)
    FOR8(TBUILD)

    float s0e = 1.0f, s0o = 1.0f;
    float s1e = 1.0f, s1o = 1.0f;
    const int wbase = rowg * RSW + l15;

    const float2* pl0 = (const float2*)&incL[2 * lane];
    const float2* pl1 = (const float2*)&incL[P1W + 2 * lane];

    for (int band = 0; band < 8; ++band) {
        int arow = band * 16 + l15; if (arow > 126) arow = 126;
        const float* ap0 = U0 + (size_t)arow * DD + k8;
        const float* ap1 = U1 + (size_t)arow * DD + k8;
        bf16x8 a0k0 = dfrag_hi(ap0,      ap0 + DD);
        bf16x8 a0k1 = dfrag_hi(ap0 + 32, ap0 + DD + 32);
        bf16x8 a1k0 = dfrag_hi(ap1,      ap1 + DD);
        bf16x8 a1k1 = dfrag_hi(ap1 + 32, ap1 + DD + 32);

        FOR8(CTSTEP2)

        float2 e0 = pl0[0],   e1 = pl1[0];
        float2 f0 = pl0[RS2], f1 = pl1[RS2];
        #pragma unroll
        for (int r = 0; r < 14; ++r) {
            float2 n0 = pl0[(r + 2) * RS2];
            float2 n1 = pl1[(r + 2) * RS2];
            SCANROW2C(e0, e1)
            e0 = f0; e1 = f1; f0 = n0; f1 = n1;
        }
        SCANROW2C(e0, e1)
        if (band < 7) { SCANROW2C(f0, f1) }
    }

    if (lane == 63) {
        float* kg = Kout + (size_t)g * 4096;
        kg[a0 * 64 + bcol] = s0o;
        if (!dup) kg[a1 * 64 + bcol] = s1o;
    }
}

// ================= ABLATION A: staging only (no scan) ========================
__global__ __launch_bounds__(64, 3) void abl_stage_kernel(
        const float* __restrict__ X, const float* __restrict__ Y,
        float* __restrict__ ws, unsigned wslim)
{
    const int bid = blockIdx.x;
    int g, a0, a1, bcol;
    if (bid < 2112) {
        g = bid < 1056 ? 0 : 1;
        const int t = bid - g * 1056;
        bcol = (int)(2.0f * sqrtf((float)t + 1.0f));
        if (bcol > 63) bcol = 63;
        while (bcol > 0  && ((bcol + 1) * (bcol + 1)) / 4 > t) --bcol;
        while (bcol < 63 && ((bcol + 2) * (bcol + 2)) / 4 <= t) ++bcol;
        const int j = t - ((bcol + 1) * (bcol + 1)) / 4;
        a0 = 2 * j; a1 = 2 * j + 1;
        if (a1 > bcol) a1 = a0;
    } else {
        const int t = bid - 2112;
        g = 2; bcol = t & 63;
        a0 = (t >> 6) * 2; a1 = a0 + 1;
    }

    const float* __restrict__ Ub = (g == 1 ? Y : X);
    const float* __restrict__ U0 = Ub + (size_t)a0 * (MM * DD);
    const float* __restrict__ U1 = Ub + (size_t)a1 * (MM * DD);
    const float* __restrict__ V  = (g == 0 ? X : Y) + (size_t)bcol * (MM * DD);

    const int lane = threadIdx.x;
    const int l15  = lane & 15;
    const int k8   = (lane >> 4) * 8;
    const int rowg = (lane >> 4) * 4;

    __shared__ float incL[2 * P1W];

    FOR8(TBDECL)
    FOR8(TBUILD)

    const int wbase = rowg * RSW + l15;

    for (int band = 0; band < 8; ++band) {
        int arow = band * 16 + l15; if (arow > 126) arow = 126;
        const float* ap0 = U0 + (size_t)arow * DD + k8;
        const float* ap1 = U1 + (size_t)arow * DD + k8;
        bf16x8 a0k0 = dfrag_hi(ap0,      ap0 + DD);
        bf16x8 a0k1 = dfrag_hi(ap0 + 32, ap0 + DD + 32);
        bf16x8 a1k0 = dfrag_hi(ap1,      ap1 + DD);
        bf16x8 a1k1 = dfrag_hi(ap1 + 32, ap1 + DD + 32);

        FOR8(CTSTEP2)

        asm volatile("" ::: "memory");   // keep all ds_writes live (no DCE)
    }

    const float junk = incL[lane] + incL[P1W + lane];
    const unsigned idx = 12288u + (unsigned)bid;
    if (lane == 63 && (idx + 1u) * 4u <= wslim) ws[idx] = junk;
}

// ================= ABLATION B: scan only (planes pre-filled) =================
__global__ __launch_bounds__(64, 3) void abl_scan_kernel(
        float* __restrict__ ws, unsigned wslim)
{
    const int bid  = blockIdx.x;
    const int lane = threadIdx.x;

    __shared__ float incL[2 * P1W];
    for (int i = lane; i < 2 * P1W; i += 64) incL[i] = 0.001f;

    float s0e = 1.0f, s0o = 1.0f;
    float s1e = 1.0f, s1o = 1.0f;

    const float2* pl0 = (const float2*)&incL[2 * lane];
    const float2* pl1 = (const float2*)&incL[P1W + 2 * lane];

    for (int band = 0; band < 8; ++band) {
        // CSE breaker: one write per band -> compiler must reload plane reads
        incL[(band & 1) * P1W + lane] = 0.001f + 1e-6f * (float)band;

        float2 e0 = pl0[0],   e1 = pl1[0];
        float2 f0 = pl0[RS2], f1 = pl1[RS2];
        #pragma unroll
        for (int r = 0; r < 14; ++r) {
            float2 n0 = pl0[(r + 2) * RS2];
            float2 n1 = pl1[(r + 2) * RS2];
            SCANROW2C(e0, e1)
            e0 = f0; e1 = f1; f0 = n0; f1 = n1;
        }
        SCANROW2C(e0, e1)
        if (band < 7) { SCANROW2C(f0, f1) }
    }

    const unsigned idx = 16448u + (unsigned)bid;
    if (lane == 63 && (idx + 1u) * 4u <= wslim) ws[idx] = s0o + s1o;
}

// ================= reducer (unchanged) =======================================
__global__ void sig_reduce_kernel(const float* __restrict__ X,
                                  const float* __restrict__ Y,
                                  const float* __restrict__ Kws,
                                  float* __restrict__ out)
{
    const int t = threadIdx.x;
    double accK = 0.0, acc2 = 0.0;
    for (int i = t; i < 4096; i += 256) {
        const int a = i >> 6, b = i & 63;
        if (a <= b) {
            const double w = (a == b) ? 1.0 : 2.0;
            accK += w * (double)Kws[i];
            accK += w * (double)Kws[4096 + i];
        }
        accK -= 2.0 * (double)Kws[8192 + i];
        const float df = X[(size_t)a * (MM * DD) + b] - Y[(size_t)a * (MM * DD) + b];
        acc2 += (double)df * (double)df;
    }
    __shared__ double red[256];
    red[t] = accK / 4096.0 + acc2 / 4096.0;
    __syncthreads();
    for (int s = 128; s > 0; s >>= 1) {
        if (t < s) red[t] += red[t + s];
        __syncthreads();
    }
    if (t == 0) out[0] = (float)red[0];
}

extern "C" void kernel_launch(void* const* d_in, const int* in_sizes, int n_in,
                              void* d_out, int out_size, void* d_ws, size_t ws_size,
                              hipStream_t stream) {
    const float* X = (const float*)d_in[0];
    const float* Y = (const float*)d_in[1];
    float* Kws = (float*)d_ws;          // 3 * 4096 floats (+ ablation scratch)
    float* out = (float*)d_out;
    const unsigned wslim = (unsigned)(ws_size > 0xFFFFFFFFull ? 0xFFFFFFFFull : ws_size);

    sig_goursat_kernel<<<dim3(4160), dim3(64), 0, stream>>>(X, Y, Kws);
    abl_stage_kernel  <<<dim3(4160), dim3(64), 0, stream>>>(X, Y, Kws, wslim);
    abl_scan_kernel   <<<dim3(4160), dim3(64), 0, stream>>>(Kws, wslim);
    sig_reduce_kernel <<<dim3(1), dim3(256), 0, stream>>>(X, Y, Kws, out);
}

// Round 16
// 145.939 us; speedup vs baseline: 1.6798x; 1.6798x over previous
//
#include <hip/hip_runtime.h>
#include <math.h>

#define DD 64      // feature dim
#define MM 128     // time points per path
#define RSW 132    // plane row stride in words: write banks 2-way, read banks 2-way (free)
#define PWORDS (16 * RSW)    // 2112 words = 8448 B per wave

typedef float  f32x4v __attribute__((ext_vector_type(4)));
typedef __bf16 bf16x8 __attribute__((ext_vector_type(8)));

#define FOR8(F) F(0) F(1) F(2) F(3) F(4) F(5) F(6) F(7)

union FragU { unsigned int u[4]; bf16x8 v; };

// RNE f32x2 -> packed bf16x2
__device__ __forceinline__ unsigned cvtpk(float lo, float hi) {
    unsigned r;
    asm("v_cvt_pk_bf16_f32 %0, %1, %2" : "=v"(r) : "v"(lo), "v"(hi));
    return r;
}

// bf16 frag of (row1 - row0), 8 consecutive floats (hi bits, RNE)
__device__ __forceinline__ bf16x8 dfrag_hi(const float* __restrict__ r0,
                                           const float* __restrict__ r1) {
    float4 a0 = *(const float4*)r0, a1 = *(const float4*)(r0 + 4);
    float4 b0 = *(const float4*)r1, b1 = *(const float4*)(r1 + 4);
    FragU f;
    f.u[0] = cvtpk(b0.x - a0.x, b0.y - a0.y);
    f.u[1] = cvtpk(b0.z - a0.z, b0.w - a0.w);
    f.u[2] = cvtpk(b1.x - a1.x, b1.y - a1.y);
    f.u[3] = cvtpk(b1.z - a1.z, b1.w - a1.w);
    return f.v;
}

// ---- wave64 inclusive add-scan via DPP (proven rounds 2-15) ----
template<int CTRL, int RM, bool BC>
__device__ __forceinline__ float dpp_add(float x) {
    int t = __builtin_amdgcn_update_dpp(0, __float_as_int(x), CTRL, RM, 0xf, BC);
    return x + __int_as_float(t);
}
__device__ __forceinline__ float wave_incl_scan(float x) {
    x = dpp_add<0x111, 0xf, true >(x);   // row_shr:1
    x = dpp_add<0x112, 0xf, true >(x);   // row_shr:2
    x = dpp_add<0x114, 0xf, true >(x);   // row_shr:4
    x = dpp_add<0x118, 0xf, true >(x);   // row_shr:8
    x = dpp_add<0x142, 0xa, false>(x);   // row_bcast:15 -> rows 1,3
    x = dpp_add<0x143, 0xc, false>(x);   // row_bcast:31 -> rows 2,3
    return x;
}

// ROUND 16: clean residency doubling. r15 ablation: stage+scan each <108us,
// sum 134 vs full 108 -> no dominant phase; everything is latency-bound at
// 2.25 waves/SIMD (the 16.9KB/1-wave-block LDS cap). Fix: ONE pair per wave
// (live ~110 regs, under the 128 cap -- no r13 spill), 4 independent waves
// per 256-thread block, per-wave f32 plane (8.4KB x 4 = 33.8KB/block), no
// barriers. LDS: 4 blocks/CU x 4 waves = 16 waves/CU; (256,4) reg cap gives
// 4/SIMD. Both limits align at 4 waves/SIMD = 1.8x r11.
// Sentinels: WRITE_SIZE ~0.26MB (spill), LDS_Block_Size ~33.8KB.
__global__ __launch_bounds__(256, 4) void sig_goursat_kernel(
        const float* __restrict__ X, const float* __restrict__ Y,
        float* __restrict__ Kout)
{
    const int tid  = threadIdx.x;
    const int wid  = tid >> 6;
    const int lane = tid & 63;
    const int t    = blockIdx.x * 4 + wid;   // global wave id, 0..8255

    int g, a, b;
    if (t < 4160) {                  // symmetric grams, triangular index
        g = t < 2080 ? 0 : 1;
        const int u = t - g * 2080;
        float sq = sqrtf(4160.25f - 2.0f * (float)u);
        a = (int)(64.5f - sq);
        if (a < 0) a = 0; if (a > 63) a = 63;
        while (a > 0  && (a * (129 - a)) / 2 > u) --a;
        while (a < 63 && ((a + 1) * (128 - a)) / 2 <= u) ++a;
        b = a + (u - (a * (129 - a)) / 2);
    } else {
        const int u = t - 4160;
        g = 2; a = u >> 6; b = u & 63;
    }

    const float* __restrict__ U = (g == 1 ? Y : X) + (size_t)a * (MM * DD);
    const float* __restrict__ V = (g == 0 ? X : Y) + (size_t)b * (MM * DD);

    const int l15  = lane & 15;
    const int k8   = (lane >> 4) * 8;         // k-offset of this lane's frag
    const int rowg = (lane >> 4) * 4;         // C/D row group base

    __shared__ float incL4[4][PWORDS];        // per-wave f32 inc plane
    float* __restrict__ incL = incL4[wid];

    // ---- B-frag register table: 16 named bf16x8 (64 regs), built once ----
#define TBDECL(ct) bf16x8 tb0_##ct, tb1_##ct;
    FOR8(TBDECL)
#define TBUILD(ct) { int brow_ = ct * 16 + l15; if (brow_ > 126) brow_ = 126; \
        const float* vp_ = V + (size_t)brow_ * DD + k8; \
        tb0_##ct = dfrag_hi(vp_,      vp_ + DD); \
        tb1_##ct = dfrag_hi(vp_ + 32, vp_ + DD + 32); }
    FOR8(TBUILD)

    float KL0 = 1.0f, KL1 = 1.0f;             // K[0][2l], K[0][2l+1] = 1
    // writer: row-major word = row*RSW + ct*16 + l15 (banks 2-way = free)
    const int wbase = rowg * RSW + l15;

#define CTSTEP(ct) { \
        f32x4v c = {0.f, 0.f, 0.f, 0.f}; \
        c = __builtin_amdgcn_mfma_f32_16x16x32_bf16(ak0, tb0_##ct, c, 0, 0, 0); \
        c = __builtin_amdgcn_mfma_f32_16x16x32_bf16(ak1, tb1_##ct, c, 0, 0, 0); \
        const int w_ = wbase + ct * 16; \
        incL[w_]         = c[0]; \
        incL[w_ + RSW]   = c[1]; \
        incL[w_ + 2*RSW] = c[2]; \
        incL[w_ + 3*RSW] = c[3]; }

#define SCANROW1(e) { \
        const float m0 = e.x * KL0; \
        const float m1 = e.y * KL1; \
        const float t_ = m0 + m1; \
        const float S_ = wave_incl_scan(t_); \
        const float ex = S_ - t_; \
        KL1 += ex + m0; \
        KL0 += ex; }

    const float2* __restrict__ pl = (const float2*)&incL[2 * lane];

    for (int band = 0; band < 8; ++band) {
        // ---- A frags: rows p = band*16 + l15 (clamped), hi-only ----
        int arow = band * 16 + l15; if (arow > 126) arow = 126;
        const float* ap = U + (size_t)arow * DD + k8;
        bf16x8 ak0 = dfrag_hi(ap,      ap + DD);
        bf16x8 ak1 = dfrag_hi(ap + 32, ap + DD + 32);

        FOR8(CTSTEP)   // inc[16][128] for this band -> plane

        // ---- Goursat scan, depth-2 LDS prefetch (wave-private, in-order) ----
        float2 e = pl[0];                     // row stride = 66 float2s
        float2 f = pl[66];
        #pragma unroll
        for (int r = 0; r < 14; ++r) {
            float2 n = pl[(r + 2) * 66];
            SCANROW1(e)
            e = f; f = n;
        }
        SCANROW1(e)                           // row 14
        if (band < 7) { SCANROW1(f) }         // row 15 (p=127 phantom on band 7)
    }

    if (lane == 63) Kout[(size_t)g * 4096 + a * 64 + b] = KL1;   // K[127][127]
}

// Deterministic weighted reduction + the mean((X0-Y0)^2) term.
__global__ void sig_reduce_kernel(const float* __restrict__ X,
                                  const float* __restrict__ Y,
                                  const float* __restrict__ Kws,
                                  float* __restrict__ out)
{
    const int t = threadIdx.x;
    double accK = 0.0, acc2 = 0.0;
    for (int i = t; i < 4096; i += 256) {
        const int a = i >> 6, b = i & 63;
        if (a <= b) {
            const double w = (a == b) ? 1.0 : 2.0;
            accK += w * (double)Kws[i];           // XX
            accK += w * (double)Kws[4096 + i];    // YY
        }
        accK -= 2.0 * (double)Kws[8192 + i];      // XY
        const float df = X[(size_t)a * (MM * DD) + b] - Y[(size_t)a * (MM * DD) + b];
        acc2 += (double)df * (double)df;
    }
    __shared__ double red[256];
    red[t] = accK / 4096.0 + acc2 / 4096.0;
    __syncthreads();
    for (int s = 128; s > 0; s >>= 1) {
        if (t < s) red[t] += red[t + s];
        __syncthreads();
    }
    if (t == 0) out[0] = (float)red[0];
}

extern "C" void kernel_launch(void* const* d_in, const int* in_sizes, int n_in,
                              void* d_out, int out_size, void* d_ws, size_t ws_size,
                              hipStream_t stream) {
    const float* X = (const float*)d_in[0];
    const float* Y = (const float*)d_in[1];
    float* Kws = (float*)d_ws;          // 3 * 4096 floats
    float* out = (float*)d_out;

    sig_goursat_kernel<<<dim3(2064), dim3(256), 0, stream>>>(X, Y, Kws);
    sig_reduce_kernel<<<dim3(1), dim3(256), 0, stream>>>(X, Y, Kws, out);
}

// Round 17
// 128.034 us; speedup vs baseline: 1.9147x; 1.1398x over previous
//
#include <hip/hip_runtime.h>
#include <math.h>

#define DD 64      // feature dim
#define MM 128     // time points per path
#define PSTR 66    // packed plane row stride (u32): reads (lane+2r)%32 = 2-way free
#define PWORDS (16 * PSTR)   // 1056 u32 = 4224 B per stream plane

typedef float  f32x4v __attribute__((ext_vector_type(4)));
typedef __bf16 bf16x8 __attribute__((ext_vector_type(8)));

#define FOR8(F) F(0) F(1) F(2) F(3) F(4) F(5) F(6) F(7)

union FragU { unsigned int u[4]; bf16x8 v; };

// RNE f32x2 -> packed bf16x2
__device__ __forceinline__ unsigned cvtpk(float lo, float hi) {
    unsigned r;
    asm("v_cvt_pk_bf16_f32 %0, %1, %2" : "=v"(r) : "v"(lo), "v"(hi));
    return r;
}

// quad_perm [1,0,3,2]: swap adjacent lanes (lane ^ 1)
__device__ __forceinline__ float qswap(float x) {
    int t = __builtin_amdgcn_update_dpp(0, __float_as_int(x), 0xB1, 0xF, 0xF, true);
    return __int_as_float(t);
}

// bf16 frag of (row1 - row0), 8 consecutive floats (hi bits, RNE)
__device__ __forceinline__ bf16x8 dfrag_hi(const float* __restrict__ r0,
                                           const float* __restrict__ r1) {
    float4 a0 = *(const float4*)r0, a1 = *(const float4*)(r0 + 4);
    float4 b0 = *(const float4*)r1, b1 = *(const float4*)(r1 + 4);
    FragU f;
    f.u[0] = cvtpk(b0.x - a0.x, b0.y - a0.y);
    f.u[1] = cvtpk(b0.z - a0.z, b0.w - a0.w);
    f.u[2] = cvtpk(b1.x - a1.x, b1.y - a1.y);
    f.u[3] = cvtpk(b1.z - a1.z, b1.w - a1.w);
    return f.v;
}

template<int CTRL, int RM, bool BC>
__device__ __forceinline__ float dpp_add(float x) {
    int t = __builtin_amdgcn_update_dpp(0, __float_as_int(x), CTRL, RM, 0xf, BC);
    return x + __int_as_float(t);
}

// 4 INDEPENDENT wave64 inclusive scans, levels interleaved across streams so
// the 3 other chains fill each chain's DPP hazard slots (r15 ablation: the
// serial scan chain is the pole; r16: extra waves don't fill it).
__device__ __forceinline__ void scan4(float& x0, float& x1, float& x2, float& x3) {
#define LVL(CTRL, RM, BC) \
    x0 = dpp_add<CTRL, RM, BC>(x0); \
    x1 = dpp_add<CTRL, RM, BC>(x1); \
    x2 = dpp_add<CTRL, RM, BC>(x2); \
    x3 = dpp_add<CTRL, RM, BC>(x3);
    LVL(0x111, 0xf, true)   // row_shr:1
    LVL(0x112, 0xf, true)   // row_shr:2
    LVL(0x114, 0xf, true)   // row_shr:4
    LVL(0x118, 0xf, true)   // row_shr:8
    LVL(0x142, 0xa, false)  // row_bcast:15 -> rows 1,3
    LVL(0x143, 0xc, false)  // row_bcast:31 -> rows 2,3
#undef LVL
}

// ROUND 17: FOUR pairs per wave sharing the V column. One wave per block.
// Packed-bf16 planes (r13-verified layout, absmax 0.0): 4 x 4.2 KB = 16.9 KB.
// Triangular columns 4-packed: col b has floor(b/4)+1 waves;
// off(b) = (m+1)*(2m+r), m=b>>2, r=b&3 (off(64)=544). Grid: 544*2+1024 = 2112.
__global__ __launch_bounds__(64, 3) void sig_goursat_kernel(
        const float* __restrict__ X, const float* __restrict__ Y,
        float* __restrict__ Kout)
{
#define OFFB(bb) (((((bb) >> 2) + 1)) * (2 * ((bb) >> 2) + ((bb) & 3)))
    const int t = blockIdx.x;
    int g, b, j;
    if (t < 1088) {                    // symmetric grams, column 4-packed tri
        g = t < 544 ? 0 : 1;
        const int u = t - g * 544;
        int bb = (int)sqrtf(8.0f * (float)u + 1.0f);
        if (bb > 63) bb = 63;
        while (bb > 0  && OFFB(bb) > u) --bb;
        while (bb < 63 && OFFB(bb + 1) <= u) ++bb;
        b = bb;
        j = u - OFFB(bb);
    } else {
        const int u = t - 1088;
        g = 2; b = u & 63; j = u >> 6;
    }
    const int a0r = 4 * j, a1r = 4 * j + 1, a2r = 4 * j + 2, a3r = 4 * j + 3;
    const bool tri = (g < 2);
    const int a0 = (tri && a0r > b) ? b : a0r;
    const int a1 = (tri && a1r > b) ? b : a1r;
    const int a2 = (tri && a2r > b) ? b : a2r;
    const int a3 = (tri && a3r > b) ? b : a3r;

    const float* __restrict__ Ub = (g == 1 ? Y : X);
    const float* __restrict__ U0 = Ub + (size_t)a0 * (MM * DD);
    const float* __restrict__ U1 = Ub + (size_t)a1 * (MM * DD);
    const float* __restrict__ U2 = Ub + (size_t)a2 * (MM * DD);
    const float* __restrict__ U3 = Ub + (size_t)a3 * (MM * DD);
    const float* __restrict__ V  = (g == 0 ? X : Y) + (size_t)b * (MM * DD);

    const int lane = threadIdx.x;
    const int l15  = lane & 15;
    const int k8   = (lane >> 4) * 8;         // k-offset of this lane's frag
    const int rowg = (lane >> 4) * 4;         // C/D row group base
    const int par  = l15 & 1;

    __shared__ unsigned incL[4 * PWORDS];     // 4 packed-bf16 stream planes
    unsigned* __restrict__ pl0 = incL;
    unsigned* __restrict__ pl1 = incL + PWORDS;
    unsigned* __restrict__ pl2 = incL + 2 * PWORDS;
    unsigned* __restrict__ pl3 = incL + 3 * PWORDS;

    // ---- shared B-frag register table: 16 named bf16x8 (64 regs) ----
#define TBDECL(ct) bf16x8 tb0_##ct, tb1_##ct;
    FOR8(TBDECL)
#define TBUILD(ct) { int brow_ = ct * 16 + l15; if (brow_ > 126) brow_ = 126; \
        const float* vp_ = V + (size_t)brow_ * DD + k8; \
        tb0_##ct = dfrag_hi(vp_,      vp_ + DD); \
        tb1_##ct = dfrag_hi(vp_ + 32, vp_ + DD + 32); }
    FOR8(TBUILD)

    float KL0_0 = 1.f, KL1_0 = 1.f, KL0_1 = 1.f, KL1_1 = 1.f;
    float KL0_2 = 1.f, KL1_2 = 1.f, KL0_3 = 1.f, KL1_3 = 1.f;

    // packed writer (r13-verified): even l15 lanes own rows rowg+0/1,
    // odd own rowg+2/3; word = row*PSTR + ct*8 + (l15>>1)
    const int wA = (rowg + 2 * par) * PSTR + (l15 >> 1);
    const int wB = wA + PSTR;

#define CTSTEP1(ct, s) { \
        f32x4v c = {0.f, 0.f, 0.f, 0.f}; \
        c = __builtin_amdgcn_mfma_f32_16x16x32_bf16(ak0_##s, tb0_##ct, c, 0, 0, 0); \
        c = __builtin_amdgcn_mfma_f32_16x16x32_bf16(ak1_##s, tb1_##ct, c, 0, 0, 0); \
        const float n0 = qswap(c[0]); const float n1 = qswap(c[1]); \
        const float n2 = qswap(c[2]); const float n3 = qswap(c[3]); \
        const float loA = par ? n2 : c[0]; const float hiA = par ? c[2] : n0; \
        const float loB = par ? n3 : c[1]; const float hiB = par ? c[3] : n1; \
        pl##s[wA + (ct) * 8] = cvtpk(loA, hiA); \
        pl##s[wB + (ct) * 8] = cvtpk(loB, hiB); }
#define CTSTEP4(ct) CTSTEP1(ct, 0) CTSTEP1(ct, 1) CTSTEP1(ct, 2) CTSTEP1(ct, 3)

    // quad scan row: unpack 4 packed words, 4 independent scans interleaved
#define SQUAD(w0_, w1_, w2_, w3_) { \
        const float iE0 = __uint_as_float((w0_) << 16); \
        const float iO0 = __uint_as_float((w0_) & 0xffff0000u); \
        const float iE1 = __uint_as_float((w1_) << 16); \
        const float iO1 = __uint_as_float((w1_) & 0xffff0000u); \
        const float iE2 = __uint_as_float((w2_) << 16); \
        const float iO2 = __uint_as_float((w2_) & 0xffff0000u); \
        const float iE3 = __uint_as_float((w3_) << 16); \
        const float iO3 = __uint_as_float((w3_) & 0xffff0000u); \
        const float m00 = iE0 * KL0_0, m10 = iO0 * KL1_0; \
        const float m01 = iE1 * KL0_1, m11 = iO1 * KL1_1; \
        const float m02 = iE2 * KL0_2, m12 = iO2 * KL1_2; \
        const float m03 = iE3 * KL0_3, m13 = iO3 * KL1_3; \
        const float q0 = m00 + m10, q1 = m01 + m11; \
        const float q2 = m02 + m12, q3 = m03 + m13; \
        float s0 = q0, s1 = q1, s2 = q2, s3 = q3; \
        scan4(s0, s1, s2, s3); \
        const float ex0 = s0 - q0, ex1 = s1 - q1; \
        const float ex2 = s2 - q2, ex3 = s3 - q3; \
        KL1_0 += ex0 + m00;  KL0_0 += ex0; \
        KL1_1 += ex1 + m01;  KL0_1 += ex1; \
        KL1_2 += ex2 + m02;  KL0_2 += ex2; \
        KL1_3 += ex3 + m03;  KL0_3 += ex3; }

    const unsigned* __restrict__ pr0 = pl0 + lane;
    const unsigned* __restrict__ pr1 = pl1 + lane;
    const unsigned* __restrict__ pr2 = pl2 + lane;
    const unsigned* __restrict__ pr3 = pl3 + lane;

    for (int band = 0; band < 8; ++band) {
        // ---- A frags, 4 streams, hi-only: rows p = band*16 + l15 ----
        int arow = band * 16 + l15; if (arow > 126) arow = 126;
        const size_t aoff = (size_t)arow * DD + k8;
        bf16x8 ak0_0, ak1_0, ak0_1, ak1_1, ak0_2, ak1_2, ak0_3, ak1_3;
        { const float* ap = U0 + aoff; ak0_0 = dfrag_hi(ap, ap + DD); ak1_0 = dfrag_hi(ap + 32, ap + DD + 32); }
        { const float* ap = U1 + aoff; ak0_1 = dfrag_hi(ap, ap + DD); ak1_1 = dfrag_hi(ap + 32, ap + DD + 32); }
        { const float* ap = U2 + aoff; ak0_2 = dfrag_hi(ap, ap + DD); ak1_2 = dfrag_hi(ap + 32, ap + DD + 32); }
        { const float* ap = U3 + aoff; ak0_3 = dfrag_hi(ap, ap + DD); ak1_3 = dfrag_hi(ap + 32, ap + DD + 32); }

        FOR8(CTSTEP4)   // inc bands (packed bf16) -> 4 planes

        // ---- quad Goursat scan, depth-2 LDS prefetch per stream ----
        unsigned e0 = pr0[0],    e1 = pr1[0],    e2 = pr2[0],    e3 = pr3[0];
        unsigned f0 = pr0[PSTR], f1 = pr1[PSTR], f2 = pr2[PSTR], f3 = pr3[PSTR];
        #pragma unroll
        for (int r = 0; r < 13; ++r) {
            unsigned n0 = pr0[(r + 2) * PSTR];
            unsigned n1 = pr1[(r + 2) * PSTR];
            unsigned n2 = pr2[(r + 2) * PSTR];
            unsigned n3 = pr3[(r + 2) * PSTR];
            SQUAD(e0, e1, e2, e3)
            e0 = f0; e1 = f1; e2 = f2; e3 = f3;
            f0 = n0; f1 = n1; f2 = n2; f3 = n3;
        }
        if (band < 7) {
            unsigned n0 = pr0[15 * PSTR], n1 = pr1[15 * PSTR];
            unsigned n2 = pr2[15 * PSTR], n3 = pr3[15 * PSTR];
            SQUAD(e0, e1, e2, e3)                 // row 13
            e0 = f0; e1 = f1; e2 = f2; e3 = f3;
            f0 = n0; f1 = n1; f2 = n2; f3 = n3;
            SQUAD(e0, e1, e2, e3)                 // row 14
            SQUAD(f0, f1, f2, f3)                 // row 15
        } else {
            SQUAD(e0, e1, e2, e3)                 // row 13
            SQUAD(f0, f1, f2, f3)                 // row 14 (p=127 phantom)
        }
    }

    if (lane == 63) {
        float* kg = Kout + (size_t)g * 4096;
        kg[a0 * 64 + b] = KL1_0;
        if (!tri || a1r <= b) kg[a1 * 64 + b] = KL1_1;
        if (!tri || a2r <= b) kg[a2 * 64 + b] = KL1_2;
        if (!tri || a3r <= b) kg[a3 * 64 + b] = KL1_3;
    }
}

// Deterministic weighted reduction + the mean((X0-Y0)^2) term.
__global__ void sig_reduce_kernel(const float* __restrict__ X,
                                  const float* __restrict__ Y,
                                  const float* __restrict__ Kws,
                                  float* __restrict__ out)
{
    const int t = threadIdx.x;
    double accK = 0.0, acc2 = 0.0;
    for (int i = t; i < 4096; i += 256) {
        const int a = i >> 6, b = i & 63;
        if (a <= b) {
            const double w = (a == b) ? 1.0 : 2.0;
            accK += w * (double)Kws[i];           // XX
            accK += w * (double)Kws[4096 + i];    // YY
        }
        accK -= 2.0 * (double)Kws[8192 + i];      // XY
        const float df = X[(size_t)a * (MM * DD) + b] - Y[(size_t)a * (MM * DD) + b];
        acc2 += (double)df * (double)df;
    }
    __shared__ double red[256];
    red[t] = accK / 4096.0 + acc2 / 4096.0;
    __syncthreads();
    for (int s = 128; s > 0; s >>= 1) {
        if (t < s) red[t] += red[t + s];
        __syncthreads();
    }
    if (t == 0) out[0] = (float)red[0];
}

extern "C" void kernel_launch(void* const* d_in, const int* in_sizes, int n_in,
                              void* d_out, int out_size, void* d_ws, size_t ws_size,
                              hipStream_t stream) {
    const float* X = (const float*)d_in[0];
    const float* Y = (const float*)d_in[1];
    float* Kws = (float*)d_ws;          // 3 * 4096 floats
    float* out = (float*)d_out;

    sig_goursat_kernel<<<dim3(2112), dim3(64), 0, stream>>>(X, Y, Kws);
    sig_reduce_kernel<<<dim3(1), dim3(256), 0, stream>>>(X, Y, Kws, out);
}